// Round 11
// baseline (204.995 us; speedup 1.0000x reference)
//
#include <hip/hip_runtime.h>
#include <cstdint>

// y = clip(round((x @ W^T) * (sx*sw/sy)), -128, 127), M=8192 N=4096 K=4096 int8.
// Pass 1 (pack): int32 -> int8, fragment-major (verified rounds 6-10):
//   [mb (256 rows)][h 0..63 (K/64B)][rf 0..15][lane*16], lane = kl*16+fr ->
//   rows mb*256+rf*16+fr, K-bytes h*64+kl*16..+15 (exact mfma_i32_16x16x64_i8
//   operand order). A fragment IS a coalesced global_load_dwordx4.
// Pass 2 (GEMM): round-10 analysis: LDS port (96 reads + 32KB DMA ~ 1408cyc)
//   > MFMA (1306cyc) per unit -> LDS is the binding pipe. Fix: A is NOT
//   staged -- each wave loads its own A-frags direct from L1/L2 (wn4-quads
//   share lines; A panels are XCD-local: 4 x 1MB = L2). Only B goes through
//   LDS (ring-4 x 16KB, staged 3 subtiles ahead). LDS port drops to ~512cyc
//   << MFMA. ONE barrier per subtile (wait-then-barrier: per-wave vmcnt(10)
//   proves own B-DMA(h+1) landed pre-BAR; slot (h+3)&3 overwrite separated
//   from its last reader by BAR(h)). Reg dbuf X/Y kept; vmcnt counted
//   (10/10/8), never drained mid-loop.

#define MDIM 8192
#define NDIM 4096
#define KDIM 4096
#define NH 64  // K-subtiles of 64 bytes

typedef int v4i __attribute__((ext_vector_type(4)));

#define FENCE() asm volatile("" ::: "memory")
#define BARX()                    \
  do {                            \
    FENCE();                      \
    __builtin_amdgcn_s_barrier(); \
    FENCE();                      \
  } while (0)

__device__ __forceinline__ uint32_t pack4(int a, int b, int c, int d) {
  return (uint32_t)(a & 0xFF) | ((uint32_t)(b & 0xFF) << 8) |
         ((uint32_t)(c & 0xFF) << 16) | ((uint32_t)(d & 0xFF) << 24);
}

// ---------- pack: gather int32 -> fragment-major int8 + scale_y tail ----------
__global__ __launch_bounds__(256) void pack_kernel(
    const int* __restrict__ x32, const int* __restrict__ w32,
    const float* __restrict__ sy, uint8_t* __restrict__ x8f,
    uint8_t* __restrict__ w8f, float* __restrict__ tail) {
  const int t = blockIdx.x * 256 + threadIdx.x;
  if (t < NDIM) tail[t] = sy[t];
  const int NXC = (MDIM / 16) * KDIM;  // 2,097,152
  const int NWC = (NDIM / 16) * KDIM;  // 1,048,576
  if (t >= NXC + NWC) return;
  const int* src;
  uint8_t* dst;
  int chunk;
  if (t < NXC) {
    chunk = t;
    src = x32;
    dst = x8f;
  } else {
    chunk = t - NXC;
    src = w32;
    dst = w8f;
  }
  const int lpos = chunk & 63;       // lane
  const int rf = (chunk >> 6) & 15;  // 16-row fragment
  const int h = (chunk >> 10) & 63;  // K-subtile (64 bytes)
  const int mb = chunk >> 16;        // 256-row block
  const int kl = lpos >> 4, fr = lpos & 15;
  const int r = mb * 256 + rf * 16 + fr;
  const int k0 = h * 64 + kl * 16;
  const int* s = src + (size_t)r * KDIM + k0;  // 64B-aligned line
  v4i a0 = *(const v4i*)(s + 0);
  v4i a1 = *(const v4i*)(s + 4);
  v4i a2 = *(const v4i*)(s + 8);
  v4i a3 = *(const v4i*)(s + 12);
  v4i o;
  o[0] = (int)pack4(a0[0], a0[1], a0[2], a0[3]);
  o[1] = (int)pack4(a1[0], a1[1], a1[2], a1[3]);
  o[2] = (int)pack4(a2[0], a2[1], a2[2], a2[3]);
  o[3] = (int)pack4(a3[0], a3[1], a3[2], a3[3]);
  *(v4i*)(dst + (size_t)chunk * 16) = o;  // linear, fully coalesced
}

// ---------- main GEMM: direct-A from L1/L2, B via LDS ring-4 -------------------
// 512 threads = 8 waves (2M x 4N), per-wave output 128x64, acc 8x4 frags.
// LDS: 4 slots x 16KB (slot = h&3), B-tile only.
__global__ __launch_bounds__(512, 2) void gemm_kernel(
    const uint8_t* __restrict__ A8, const uint8_t* __restrict__ B8,
    const float* __restrict__ sxp, const float* __restrict__ swp,
    const float* __restrict__ syp, float* __restrict__ out) {
  __shared__ __align__(16) uint8_t lds[65536];

  const int tid = threadIdx.x;
  const int lane = tid & 63;
  const int wave = tid >> 6;

  // XCD-aware swizzle: nwg = 512 (divisible by 8 -> bijective); 64 wgs/XCD
  // = 4 mb x 16 nb -> A working set 4MB = one XCD L2.
  const int wg = ((int)blockIdx.x % 8) * 64 + (int)blockIdx.x / 8;
  const int mb = wg >> 4;  // 0..31
  const int nb = wg & 15;  // 0..15

  const int wm2 = wave >> 2;  // 0..1
  const int wn4 = wave & 3;   // 0..3

  const uint8_t* Apan = A8 + ((size_t)mb << 20) +
                        ((uint32_t)(wm2 * 8) << 10) + (uint32_t)lane * 16;
  const uint8_t* Bpan = B8 + ((size_t)nb << 20);

  const uint32_t tid16 = (uint32_t)tid * 16;
  const uint32_t lane16 = (uint32_t)lane * 16;
  const uint32_t boff = ((uint32_t)(wn4 * 4) << 10) + lane16;

  v4i acc[8][4];
#pragma unroll
  for (int i = 0; i < 8; i++)
#pragma unroll
    for (int j = 0; j < 4; j++) acc[i][j] = (v4i){0, 0, 0, 0};

  auto gload = [&](const uint8_t* src, uint32_t ldsoff) {
    __builtin_amdgcn_global_load_lds(
        (const __attribute__((address_space(1))) void*)src,
        (__attribute__((address_space(3))) void*)(lds + ldsoff), 16, 0, 0);
  };
  // stage B subtile h into slot h&3 (16KB, 2 loads/thread, linear)
  auto stageB = [&](int h) {
    const uint32_t s = ((uint32_t)h & 3u) * 16384u;
    const uint8_t* src = Bpan + ((size_t)h << 14) + tid16;
    gload(src, s + tid16);
    gload(src + 8192, s + 8192u + tid16);
  };
  // direct-load wave's 8 A-fragments for subtile h (coalesced dwordx4)
  auto loadA = [&](v4i(&a)[8], int h) {
    const uint8_t* p = Apan + ((size_t)h << 14);
#pragma unroll
    for (int i = 0; i < 8; i++) a[i] = *(const v4i*)(p + (i << 10));
  };
  auto readB = [&](v4i(&b)[4], int h) {
    const uint8_t* L = lds + ((uint32_t)h & 3u) * 16384u + boff;
#pragma unroll
    for (int j = 0; j < 4; j++) b[j] = *(const v4i*)(L + (j << 10));
  };

#define MFMA32(AF, BF)                                                        \
  do {                                                                        \
    _Pragma("unroll") for (int i = 0; i < 8; i++) _Pragma(                    \
        "unroll") for (int j = 0; j < 4; j++) acc[i][j] =                     \
        __builtin_amdgcn_mfma_i32_16x16x64_i8(AF[i], BF[j], acc[i][j], 0, 0,  \
                                              0);                             \
  } while (0)

  v4i aX[8], aY[8], bX[4], bY[4];

  // prologue: B staged 3 deep; A(0) in flight
  stageB(0);
  stageB(1);
  stageB(2);
  loadA(aX, 0);
  // outstanding 14 (B0 2, B1 2, B2 2, A0 8); oldest 2 = B0 -> landed at <=12
  asm volatile("s_waitcnt vmcnt(12)" ::: "memory");
  BARX();
  readB(bX, 0);

  // steady state: iter h = {vmcnt(B(h+1) landed); BAR; stageB(h+3);
  //   loadA(h+1); readB(h+1); MFMA(h)} -- one barrier per subtile.
  for (int h = 0; h < 62; h += 2) {
    // even iter: outstanding 12 (B(h+1) 2, B(h+2) 2, A(h) consumed, A(h+1)..
    // order: B(h+1), B(h+2), A(h+... ) -> oldest 2 = B(h+1): landed at <=10
    asm volatile("s_waitcnt vmcnt(10)" ::: "memory");
    BARX();  // all waves' B(h+1) DMA landed; all reads of slot (h+3)&3 done
    stageB(h + 3);
    loadA(aY, h + 1);
    readB(bY, h + 1);
    MFMA32(aX, bX);  // compiler: vmcnt for aX, lgkm for bX (counted)

    // odd iter
    asm volatile("s_waitcnt vmcnt(10)" ::: "memory");
    BARX();
    if (h + 4 < NH) stageB(h + 4);
    loadA(aX, h + 2);
    readB(bX, h + 2);
    MFMA32(aY, bY);
  }
  // h = 62: outstanding 10 (B63 2, A62 8); oldest 2 = B63 -> <=8
  asm volatile("s_waitcnt vmcnt(8)" ::: "memory");
  BARX();
  loadA(aY, 63);
  readB(bY, 63);
  MFMA32(aX, bX);  // subtile 62
  MFMA32(aY, bY);  // subtile 63 (compiler inserts final waits)

  // epilogue: requantize, round-half-even, clip, store float
  const float s = sxp[0] * swp[0];
  const int kl = lane >> 4;
  const int fr = lane & 15;
  const int wrow = mb * 256 + wm2 * 128;
  const int wcol = nb * 256 + wn4 * 64;
#pragma unroll
  for (int j = 0; j < 4; j++) {
    const int col = wcol + j * 16 + fr;
    const float rs = s / syp[col];
#pragma unroll
    for (int i = 0; i < 8; i++) {
      const int row0 = wrow + i * 16 + kl * 4;
#pragma unroll
      for (int r = 0; r < 4; r++) {
        float v = rintf((float)acc[i][j][r] * rs);
        v = fminf(127.f, fmaxf(-128.f, v));
        out[(size_t)(row0 + r) * NDIM + col] = v;
      }
    }
  }
}

extern "C" void kernel_launch(void* const* d_in, const int* in_sizes, int n_in,
                              void* d_out, int out_size, void* d_ws, size_t ws_size,
                              hipStream_t stream) {
  const int* x32 = (const int*)d_in[0];
  const int* w32 = (const int*)d_in[1];
  const float* sx = (const float*)d_in[2];
  const float* sw = (const float*)d_in[3];
  const float* sy = (const float*)d_in[4];
  float* out = (float*)d_out;
  float* tail = out + (size_t)MDIM * NDIM;

  uint8_t* x8f = (uint8_t*)d_ws;
  uint8_t* w8f = x8f + (size_t)MDIM * KDIM;

  const int total = (MDIM / 16) * KDIM + (NDIM / 16) * KDIM;  // 3,145,728
  pack_kernel<<<total / 256, 256, 0, stream>>>(x32, w32, sy, x8f, w8f, tail);

  const int nblocks = (MDIM / 256) * (NDIM / 256);  // 512
  gemm_kernel<<<nblocks, 512, 0, stream>>>(x8f, w8f, sx, sw, sy, out);
}